// Round 9
// baseline (43784.058 us; speedup 1.0000x reference)
//
#include <hip/hip_runtime.h>
#include <hip/hip_bf16.h>

#define BB 32
#define LL 2048
#define DD 127
#define HH 256
#define OM 128
#define NSTEP 2047
#define SPIN_CAP (1 << 12)   // bounded spin: protocol bug -> wrong answer, not GPU wedge

typedef short short8 __attribute__((ext_vector_type(8)));
typedef unsigned short u16x8 __attribute__((ext_vector_type(8)));
typedef float f32x4 __attribute__((ext_vector_type(4)));

__device__ __forceinline__ unsigned short f2bf(float f) {
    union { float f; unsigned int u; } v; v.f = f;
    unsigned int u = v.u;
    return (unsigned short)((u + 0x7fffu + ((u >> 16) & 1u)) >> 16);
}
__device__ __forceinline__ float bf2f(unsigned short b) {
    union { float f; unsigned int u; } v; v.u = ((unsigned int)b) << 16;
    return v.f;
}

// LDS layout (bytes): A_hi[128][256]bf16 | A_lo[128][256]bf16 | y_s[32][256]bf16 | vfB[128]f32 | red[4][2][16]f32
#define OFF_AHI 0
#define OFF_ALO 65536
#define OFF_YS  131072
#define OFF_VFB 147456
#define OFF_RED 147968
#define SMEM_BYTES 148480

// row stride 512B, XOR-swizzle spreads 16-lane column reads across banks
__device__ __forceinline__ unsigned swz(unsigned row, unsigned bytecol) {
    return row * 512u + (bytecol ^ ((row & 7u) << 4));
}

// ws layout: slots u32[256] PACKED @0 (16 lines) | yinit f32[256][32] @1024 |
// yb0 bf16[256][32] @33792 | yb1 @50176  (total 66560 B)
#define WS_SLOTS 0
#define WS_YINIT 1024
#define WS_YB0   33792
#define WS_YB1   50176

__global__ void lcde_init(const float* __restrict__ X, const float* __restrict__ IM,
                          const float* __restrict__ IB, char* __restrict__ ws)
{
    int b = blockIdx.x, h = threadIdx.x;
    const float* xr = X + (size_t)b * LL * DD;   // X[b,0,:]
    const float* m  = IM + h * DD;
    float s = IB[h];
    for (int d = 0; d < DD; ++d) s += xr[d] * m[d];
    ((float*)(ws + WS_YINIT))[h * 32 + b] = s;                    // [k=h][b] f32
    ((unsigned short*)(ws + WS_YB0))[h * 32 + b] = f2bf(s);       // [k=h][b] bf16
    if (b == 0) ((unsigned*)(ws + WS_SLOTS))[h] = 0u;             // zero arrival slots
}

__global__ void __launch_bounds__(256, 1)
lcde_main(const float* __restrict__ X, const float* __restrict__ vfA,
          const float* __restrict__ vfB, char* __restrict__ ws,
          float* __restrict__ out)
{
    extern __shared__ char smem[];
    const int h = blockIdx.x;
    const int t = threadIdx.x;

    // ---- prologue: stage vf_A[h,:,:] into LDS as bf16 hi + bf16 residual, swizzled ----
    {
        const int o = t >> 1, kh = t & 1;
        const float* src = vfA + ((size_t)(h * OM + o)) * HH + kh * 128;
        for (int i0 = 0; i0 < 128; i0 += 8) {
            f32x4 a = *(const f32x4*)(src + i0);
            f32x4 b4 = *(const f32x4*)(src + i0 + 4);
            u16x8 hi, lo;
            for (int j = 0; j < 4; ++j) {
                float v = a[j];
                unsigned short hb = f2bf(v);
                hi[j] = hb; lo[j] = f2bf(v - bf2f(hb));
                v = b4[j];
                hb = f2bf(v);
                hi[4 + j] = hb; lo[4 + j] = f2bf(v - bf2f(hb));
            }
            unsigned bc = (unsigned)(kh * 256 + i0 * 2);
            *(u16x8*)(smem + OFF_AHI + swz(o, bc)) = hi;
            *(u16x8*)(smem + OFF_ALO + swz(o, bc)) = lo;
        }
        if (t < OM) ((float*)(smem + OFF_VFB))[t] = vfB[h * OM + t];
    }

    // f32 master state for this block's h-row lives in wave-0 registers: lane t<32 holds y[b=t][h]
    float y_reg = 0.f;
    if (t < 32) y_reg = ((const float*)(ws + WS_YINIT))[h * 32 + t];
    __syncthreads();

    unsigned* slots = (unsigned*)(ws + WS_SLOTS);
    unsigned short* yb[2] = { (unsigned short*)(ws + WS_YB0), (unsigned short*)(ws + WS_YB1) };

    const int w = t >> 6, lane = t & 63, g = lane >> 4, l15 = lane & 15;
    float* redp = (float*)(smem + OFF_RED);
    const float dt = 1.0f / 2048.0f;   // reference: dt = 1/length

    for (int n = 1; n <= NSTEP; ++n) {
        const unsigned short* ysrc = yb[(n - 1) & 1];
        unsigned short* ydst       = yb[n & 1];
        const unsigned epoch = (unsigned)(n - 1);

        // c values (global X, L2/L3-hot) + vfB — independent of y; issued before the
        // poll so their latency hides under the spin (values land in VGPRs; the
        // later cache-invalidate doesn't touch registers).
        const float tn = (float)n * (float)(1.0 / 2047.0);   // ts = linspace(0,1,L)
        float cv[2][8];   // [nt][mt*4+j]
        float vb[8];
        for (int mt = 0; mt < 2; ++mt)
            for (int j = 0; j < 4; ++j) {
                int o = 16 * (2 * w + mt) + 4 * g + j;
                int idx = mt * 4 + j;
                vb[idx] = ((const float*)(smem + OFF_VFB))[o];
                for (int nt = 0; nt < 2; ++nt) {
                    int b = 16 * nt + l15;
                    cv[nt][idx] = (o == 0) ? tn
                        : X[((size_t)b * LL + n) * DD + (o - 1)];
                }
            }

        // ---- direct-poll barrier: every wave polls all 256 packed slots ----
        {
            int guard = 0;
            for (;;) {
                unsigned v0 = __hip_atomic_load(slots + lane,       __ATOMIC_RELAXED, __HIP_MEMORY_SCOPE_AGENT);
                unsigned v1 = __hip_atomic_load(slots + lane + 64,  __ATOMIC_RELAXED, __HIP_MEMORY_SCOPE_AGENT);
                unsigned v2 = __hip_atomic_load(slots + lane + 128, __ATOMIC_RELAXED, __HIP_MEMORY_SCOPE_AGENT);
                unsigned v3 = __hip_atomic_load(slots + lane + 192, __ATOMIC_RELAXED, __HIP_MEMORY_SCOPE_AGENT);
                int ok = (v0 >= epoch) & (v1 >= epoch) & (v2 >= epoch) & (v3 >= epoch);
                if (__all(ok)) break;
                if (++guard >= SPIN_CAP) break;   // degrade to wrong answer, never wedge
                __builtin_amdgcn_s_sleep(1);
            }
            __threadfence();   // acquire: invalidate L1/L2 so staged y reads see remote writes
        }

        // ---- stage y_{n-1} (bf16, [k][b] global) -> LDS y_s[b][k], swizzled ----
        for (int i = 0; i < 4; ++i) {
            int k  = 64 * i + (t >> 2);
            int b0 = (t & 3) * 8;
            u16x8 v = *(const u16x8*)(ysrc + k * 32 + b0);
            for (int j = 0; j < 8; ++j)
                *(unsigned short*)(smem + OFF_YS + swz((unsigned)(b0 + j), (unsigned)(2 * k))) = v[j];
        }
        __syncthreads();

        // ---- u[o,b] = sum_k vfA[h,o,k] * y[b,k] via MFMA ----
        f32x4 acc[2][2] = {};
        for (int ks = 0; ks < 8; ++ks) {
            unsigned bc = 64u * ks + 16u * (unsigned)g;
            short8 a0h = *(const short8*)(smem + OFF_AHI + swz((unsigned)(16 * (2 * w) + l15), bc));
            short8 a0l = *(const short8*)(smem + OFF_ALO + swz((unsigned)(16 * (2 * w) + l15), bc));
            short8 a1h = *(const short8*)(smem + OFF_AHI + swz((unsigned)(16 * (2 * w + 1) + l15), bc));
            short8 a1l = *(const short8*)(smem + OFF_ALO + swz((unsigned)(16 * (2 * w + 1) + l15), bc));
            short8 b0  = *(const short8*)(smem + OFF_YS  + swz((unsigned)l15, bc));
            short8 b1  = *(const short8*)(smem + OFF_YS  + swz((unsigned)(16 + l15), bc));
            acc[0][0] = __builtin_amdgcn_mfma_f32_16x16x32_bf16(a0h, b0, acc[0][0], 0, 0, 0);
            acc[0][1] = __builtin_amdgcn_mfma_f32_16x16x32_bf16(a0h, b1, acc[0][1], 0, 0, 0);
            acc[1][0] = __builtin_amdgcn_mfma_f32_16x16x32_bf16(a1h, b0, acc[1][0], 0, 0, 0);
            acc[1][1] = __builtin_amdgcn_mfma_f32_16x16x32_bf16(a1h, b1, acc[1][1], 0, 0, 0);
            acc[0][0] = __builtin_amdgcn_mfma_f32_16x16x32_bf16(a0l, b0, acc[0][0], 0, 0, 0);
            acc[0][1] = __builtin_amdgcn_mfma_f32_16x16x32_bf16(a0l, b1, acc[0][1], 0, 0, 0);
            acc[1][0] = __builtin_amdgcn_mfma_f32_16x16x32_bf16(a1l, b0, acc[1][0], 0, 0, 0);
            acc[1][1] = __builtin_amdgcn_mfma_f32_16x16x32_bf16(a1l, b1, acc[1][1], 0, 0, 0);
        }

        // ---- z[b] = sum_o c[b,o] * (u[o,b] + vfB[h,o]) ----
        float p0 = 0.f, p1 = 0.f;
        for (int mt = 0; mt < 2; ++mt)
            for (int j = 0; j < 4; ++j) {
                int idx = mt * 4 + j;
                p0 += cv[0][idx] * (acc[mt][0][j] + vb[idx]);
                p1 += cv[1][idx] * (acc[mt][1][j] + vb[idx]);
            }
        p0 += __shfl_xor(p0, 16, 64);
        p0 += __shfl_xor(p0, 32, 64);
        p1 += __shfl_xor(p1, 16, 64);
        p1 += __shfl_xor(p1, 32, 64);
        if (g == 0) {
            redp[w * 32 + 0 * 16 + l15] = p0;
            redp[w * 32 + 1 * 16 + l15] = p1;
        }
        __syncthreads();

        // ---- tail: y update in registers; publish one 64B line write-through ----
        int bfi = 0;
        if (t < 32) {
            float z = redp[t] + redp[32 + t] + redp[64 + t] + redp[96 + t];
            y_reg += dt * z;
            bfi = (int)f2bf(y_reg);
            if (n == NSTEP) out[t * HH + h] = y_reg;
        }
        // pack 2 bf16 per u32 (shfl reads source VGPRs regardless of exec); lanes 0-15 store
        {
            int lo = __shfl(bfi, 2 * (t & 15), 64);
            int hi = __shfl(bfi, 2 * (t & 15) + 1, 64);
            if (t < 16) {
                unsigned word = ((unsigned)lo & 0xffffu) | ((unsigned)hi << 16);
                __hip_atomic_store((unsigned*)ydst + h * 16 + t, word,
                                   __ATOMIC_RELAXED, __HIP_MEMORY_SCOPE_AGENT);
            }
        }
        // order: y-line stores complete at coherence point before slot store issues
        asm volatile("s_waitcnt vmcnt(0)" ::: "memory");
        if (t == 0)
            __hip_atomic_store(slots + h, (unsigned)n, __ATOMIC_RELAXED, __HIP_MEMORY_SCOPE_AGENT);
    }
}

extern "C" void kernel_launch(void* const* d_in, const int* in_sizes, int n_in,
                              void* d_out, int out_size, void* d_ws, size_t ws_size,
                              hipStream_t stream) {
    const float* X   = (const float*)d_in[0];
    const float* IM  = (const float*)d_in[1];
    const float* IB  = (const float*)d_in[2];
    const float* vfA = (const float*)d_in[3];
    const float* vfB = (const float*)d_in[4];
    float* out = (float*)d_out;
    char* ws = (char*)d_ws;

    lcde_init<<<dim3(BB), dim3(HH), 0, stream>>>(X, IM, IB, ws);

    hipFuncSetAttribute(reinterpret_cast<const void*>(lcde_main),
                        hipFuncAttributeMaxDynamicSharedMemorySize, SMEM_BYTES);
    void* args[] = { (void*)&X, (void*)&vfA, (void*)&vfB, (void*)&ws, (void*)&out };
    hipLaunchCooperativeKernel(reinterpret_cast<const void*>(lcde_main),
                               dim3(HH), dim3(HH), args, SMEM_BYTES, stream);
}

// Round 13
// 15988.040 us; speedup vs baseline: 2.7386x; 2.7386x over previous
//
#include <hip/hip_runtime.h>
#include <hip/hip_bf16.h>

#define BB 32
#define LL 2048
#define DD 127
#define HH 256
#define OM 128
#define NSTEP 2047
#define SPIN_CAP (1 << 12)   // bounded spin: protocol bug -> wrong answer, not GPU wedge

typedef short short8 __attribute__((ext_vector_type(8)));
typedef unsigned short u16x8 __attribute__((ext_vector_type(8)));
typedef float f32x4 __attribute__((ext_vector_type(4)));

__device__ __forceinline__ unsigned short f2bf(float f) {
    union { float f; unsigned int u; } v; v.f = f;
    unsigned int u = v.u;
    return (unsigned short)((u + 0x7fffu + ((u >> 16) & 1u)) >> 16);
}
__device__ __forceinline__ float bf2f(unsigned short b) {
    union { float f; unsigned int u; } v; v.u = ((unsigned int)b) << 16;
    return v.f;
}

// LDS layout (bytes): A_hi[128][256]bf16 | A_lo[128][256]bf16 | y_s[32][256]bf16 | vfB[128]f32 | red[4][2][16]f32
#define OFF_AHI 0
#define OFF_ALO 65536
#define OFF_YS  131072
#define OFF_VFB 147456
#define OFF_RED 147968
#define SMEM_BYTES 148480

// row stride 512B, XOR-swizzle spreads 16-lane column reads across banks
__device__ __forceinline__ unsigned swz(unsigned row, unsigned bytecol) {
    return row * 512u + (bytecol ^ ((row & 7u) << 4));
}

// ws layout: slots u32[256] packed @0 (16 lines) | flag replicas u32[16] on 16 lines @1024 |
// yinit f32[256][32] @2048 | yb0 bf16[256][32] @34816 | yb1 @51200  (total 67584 B)
#define WS_SLOTS 0
#define WS_FLAG  1024
#define WS_YINIT 2048
#define WS_YB0   34816
#define WS_YB1   51200

__global__ void lcde_init(const float* __restrict__ X, const float* __restrict__ IM,
                          const float* __restrict__ IB, char* __restrict__ ws)
{
    int b = blockIdx.x, h = threadIdx.x;
    const float* xr = X + (size_t)b * LL * DD;   // X[b,0,:]
    const float* m  = IM + h * DD;
    float s = IB[h];
    for (int d = 0; d < DD; ++d) s += xr[d] * m[d];
    ((float*)(ws + WS_YINIT))[h * 32 + b] = s;                    // [k=h][b] f32
    ((unsigned short*)(ws + WS_YB0))[h * 32 + b] = f2bf(s);       // [k=h][b] bf16
    if (b == 0) {                                                  // zero slots + flag replicas
        ((unsigned*)ws)[h] = 0u;          // slots[256]
        ((unsigned*)ws)[256 + h] = 0u;    // flag area (256 u32 = 1024 B)
    }
}

__global__ void __launch_bounds__(256, 1)
lcde_main(const float* __restrict__ X, const float* __restrict__ vfA,
          const float* __restrict__ vfB, char* __restrict__ ws,
          float* __restrict__ out)
{
    extern __shared__ char smem[];
    const int h = blockIdx.x;
    const int t = threadIdx.x;

    // ---- prologue: stage vf_A[h,:,:] into LDS as bf16 hi + bf16 residual, swizzled ----
    {
        const int o = t >> 1, kh = t & 1;
        const float* src = vfA + ((size_t)(h * OM + o)) * HH + kh * 128;
        for (int i0 = 0; i0 < 128; i0 += 8) {
            f32x4 a = *(const f32x4*)(src + i0);
            f32x4 b4 = *(const f32x4*)(src + i0 + 4);
            u16x8 hi, lo;
            for (int j = 0; j < 4; ++j) {
                float v = a[j];
                unsigned short hb = f2bf(v);
                hi[j] = hb; lo[j] = f2bf(v - bf2f(hb));
                v = b4[j];
                hb = f2bf(v);
                hi[4 + j] = hb; lo[4 + j] = f2bf(v - bf2f(hb));
            }
            unsigned bc = (unsigned)(kh * 256 + i0 * 2);
            *(u16x8*)(smem + OFF_AHI + swz(o, bc)) = hi;
            *(u16x8*)(smem + OFF_ALO + swz(o, bc)) = lo;
        }
        if (t < OM) ((float*)(smem + OFF_VFB))[t] = vfB[h * OM + t];
    }

    // f32 master state for this block's h-row lives in wave-0 registers: lane t<32 holds y[b=t][h]
    float y_reg = 0.f;
    if (t < 32) y_reg = ((const float*)(ws + WS_YINIT))[h * 32 + t];
    __syncthreads();

    unsigned* slots   = (unsigned*)(ws + WS_SLOTS);
    unsigned* flagrep = (unsigned*)(ws + WS_FLAG);   // 16 replicas, 64B apart
    unsigned short* yb[2] = { (unsigned short*)(ws + WS_YB0), (unsigned short*)(ws + WS_YB1) };

    const int w = t >> 6, lane = t & 63, g = lane >> 4, l15 = lane & 15;
    float* redp = (float*)(smem + OFF_RED);
    const float dt = 1.0f / 2048.0f;   // reference: dt = 1/length

    for (int n = 1; n <= NSTEP; ++n) {
        const unsigned short* ysrc = yb[(n - 1) & 1];
        unsigned short* ydst       = yb[n & 1];
        const unsigned epoch = (unsigned)(n - 1);

        // c values (global X, L2/L3-hot) + vfB — independent of y; issued before the
        // wait so their latency hides under the spin.
        const float tn = (float)n * (float)(1.0 / 2047.0);   // ts = linspace(0,1,L)
        float cv[2][8];   // [nt][mt*4+j]
        float vb[8];
        for (int mt = 0; mt < 2; ++mt)
            for (int j = 0; j < 4; ++j) {
                int o = 16 * (2 * w + mt) + 4 * g + j;
                int idx = mt * 4 + j;
                vb[idx] = ((const float*)(smem + OFF_VFB))[o];
                for (int nt = 0; nt < 2; ++nt) {
                    int b = 16 * nt + l15;
                    cv[nt][idx] = (o == 0) ? tn
                        : X[((size_t)b * LL + n) * DD + (o - 1)];
                }
            }

        // ---- barrier: leader gather (block 0, 1 thread per slot) + replicated-flag broadcast ----
        if (h == 0) {
            int guard = 0;
            while (__hip_atomic_load(slots + t, __ATOMIC_RELAXED, __HIP_MEMORY_SCOPE_AGENT) < epoch
                   && ++guard < SPIN_CAP)
                __builtin_amdgcn_s_sleep(1);
            __syncthreads();   // all 256 slots observed at epoch
            if (t < 16)
                __hip_atomic_store(flagrep + t * 16, epoch, __ATOMIC_RELAXED, __HIP_MEMORY_SCOPE_AGENT);
        }
        if (t == 0) {
            int guard = 0;
            while (__hip_atomic_load(flagrep + (h & 15) * 16, __ATOMIC_RELAXED, __HIP_MEMORY_SCOPE_AGENT) < epoch
                   && ++guard < SPIN_CAP)
                __builtin_amdgcn_s_sleep(1);
            __threadfence();   // acquire: invalidate L1/L2 so staged y reads see remote writes
        }
        __syncthreads();

        // ---- stage y_{n-1} (bf16, [k][b] global) -> LDS y_s[b][k], swizzled ----
        for (int i = 0; i < 4; ++i) {
            int k  = 64 * i + (t >> 2);
            int b0 = (t & 3) * 8;
            u16x8 v = *(const u16x8*)(ysrc + k * 32 + b0);
            for (int j = 0; j < 8; ++j)
                *(unsigned short*)(smem + OFF_YS + swz((unsigned)(b0 + j), (unsigned)(2 * k))) = v[j];
        }
        __syncthreads();

        // ---- u[o,b] = sum_k vfA[h,o,k] * y[b,k] via MFMA ----
        f32x4 acc[2][2] = {};
        for (int ks = 0; ks < 8; ++ks) {
            unsigned bc = 64u * ks + 16u * (unsigned)g;
            short8 a0h = *(const short8*)(smem + OFF_AHI + swz((unsigned)(16 * (2 * w) + l15), bc));
            short8 a0l = *(const short8*)(smem + OFF_ALO + swz((unsigned)(16 * (2 * w) + l15), bc));
            short8 a1h = *(const short8*)(smem + OFF_AHI + swz((unsigned)(16 * (2 * w + 1) + l15), bc));
            short8 a1l = *(const short8*)(smem + OFF_ALO + swz((unsigned)(16 * (2 * w + 1) + l15), bc));
            short8 b0  = *(const short8*)(smem + OFF_YS  + swz((unsigned)l15, bc));
            short8 b1  = *(const short8*)(smem + OFF_YS  + swz((unsigned)(16 + l15), bc));
            acc[0][0] = __builtin_amdgcn_mfma_f32_16x16x32_bf16(a0h, b0, acc[0][0], 0, 0, 0);
            acc[0][1] = __builtin_amdgcn_mfma_f32_16x16x32_bf16(a0h, b1, acc[0][1], 0, 0, 0);
            acc[1][0] = __builtin_amdgcn_mfma_f32_16x16x32_bf16(a1h, b0, acc[1][0], 0, 0, 0);
            acc[1][1] = __builtin_amdgcn_mfma_f32_16x16x32_bf16(a1h, b1, acc[1][1], 0, 0, 0);
            acc[0][0] = __builtin_amdgcn_mfma_f32_16x16x32_bf16(a0l, b0, acc[0][0], 0, 0, 0);
            acc[0][1] = __builtin_amdgcn_mfma_f32_16x16x32_bf16(a0l, b1, acc[0][1], 0, 0, 0);
            acc[1][0] = __builtin_amdgcn_mfma_f32_16x16x32_bf16(a1l, b0, acc[1][0], 0, 0, 0);
            acc[1][1] = __builtin_amdgcn_mfma_f32_16x16x32_bf16(a1l, b1, acc[1][1], 0, 0, 0);
        }

        // ---- z[b] = sum_o c[b,o] * (u[o,b] + vfB[h,o]) ----
        float p0 = 0.f, p1 = 0.f;
        for (int mt = 0; mt < 2; ++mt)
            for (int j = 0; j < 4; ++j) {
                int idx = mt * 4 + j;
                p0 += cv[0][idx] * (acc[mt][0][j] + vb[idx]);
                p1 += cv[1][idx] * (acc[mt][1][j] + vb[idx]);
            }
        p0 += __shfl_xor(p0, 16, 64);
        p0 += __shfl_xor(p0, 32, 64);
        p1 += __shfl_xor(p1, 16, 64);
        p1 += __shfl_xor(p1, 32, 64);
        if (g == 0) {
            redp[w * 32 + 0 * 16 + l15] = p0;
            redp[w * 32 + 1 * 16 + l15] = p1;
        }
        __syncthreads();

        // ---- tail: y update in registers; publish one 64B line write-through ----
        int bfi = 0;
        if (t < 32) {
            float z = redp[t] + redp[32 + t] + redp[64 + t] + redp[96 + t];
            y_reg += dt * z;
            bfi = (int)f2bf(y_reg);
            if (n == NSTEP) out[t * HH + h] = y_reg;
        }
        // pack 2 bf16 per u32 (shfl reads source VGPRs regardless of exec); lanes 0-15 store
        {
            int lo = __shfl(bfi, 2 * (t & 15), 64);
            int hi = __shfl(bfi, 2 * (t & 15) + 1, 64);
            if (t < 16) {
                unsigned word = ((unsigned)lo & 0xffffu) | ((unsigned)hi << 16);
                __hip_atomic_store((unsigned*)ydst + h * 16 + t, word,
                                   __ATOMIC_RELAXED, __HIP_MEMORY_SCOPE_AGENT);
            }
        }
        // order: y-line stores reach the coherence point before the slot store issues
        asm volatile("s_waitcnt vmcnt(0)" ::: "memory");
        if (t == 0)
            __hip_atomic_store(slots + h, (unsigned)n, __ATOMIC_RELAXED, __HIP_MEMORY_SCOPE_AGENT);
    }
}

extern "C" void kernel_launch(void* const* d_in, const int* in_sizes, int n_in,
                              void* d_out, int out_size, void* d_ws, size_t ws_size,
                              hipStream_t stream) {
    const float* X   = (const float*)d_in[0];
    const float* IM  = (const float*)d_in[1];
    const float* IB  = (const float*)d_in[2];
    const float* vfA = (const float*)d_in[3];
    const float* vfB = (const float*)d_in[4];
    float* out = (float*)d_out;
    char* ws = (char*)d_ws;

    lcde_init<<<dim3(BB), dim3(HH), 0, stream>>>(X, IM, IB, ws);

    hipFuncSetAttribute(reinterpret_cast<const void*>(lcde_main),
                        hipFuncAttributeMaxDynamicSharedMemorySize, SMEM_BYTES);
    void* args[] = { (void*)&X, (void*)&vfA, (void*)&vfB, (void*)&ws, (void*)&out };
    hipLaunchCooperativeKernel(reinterpret_cast<const void*>(lcde_main),
                               dim3(HH), dim3(HH), args, SMEM_BYTES, stream);
}